// Round 4
// baseline (2790.188 us; speedup 1.0000x reference)
//
#include <hip/hip_runtime.h>
#include <math.h>

// B=256, N_ROIS=200, ROI_DIM=199, D=192, H=6, Dh=32, L=3, FF=576, NCLS=2
// T = 51200 tokens.
// GEMMs: bf16x3 split-precision MFMA (Ah*Bh + Ah*Bl + Al*Bh, fp32 accum).
// Attention: K/V rows are wave-uniform -> loaded via scalar s_load into SGPRs;
// inner loop is pure VALU (v_fmac v,s,v), no LDS, no VMEM.

typedef unsigned short u16;
typedef unsigned int u32;
typedef __attribute__((ext_vector_type(8))) __bf16 bf16x8;
typedef __attribute__((ext_vector_type(4))) float f32x4;
typedef __attribute__((ext_vector_type(4))) unsigned int u32x4;

__device__ __forceinline__ u16 f2bf(float x) {
    u32 u = __float_as_uint(x);
    u = (u + 0x7FFFu + ((u >> 16) & 1u)) >> 16;   // RNE
    return (u16)u;
}
__device__ __forceinline__ float bf2f(u16 h) {
    return __uint_as_float(((u32)h) << 16);
}
__device__ __forceinline__ float uf(u32 u) { return __uint_as_float(u); }

__device__ __forceinline__ float gelu_exact(float x) {
    return 0.5f * x * (1.0f + erff(x * 0.7071067811865475f));
}

__device__ __forceinline__ float wave_sum(float v) {
#pragma unroll
    for (int o = 32; o > 0; o >>= 1) v += __shfl_xor(v, o, 64);
    return v;
}
__device__ __forceinline__ float wave_max(float v) {
#pragma unroll
    for (int o = 32; o > 0; o >>= 1) v = fmaxf(v, __shfl_xor(v, o, 64));
    return v;
}

__device__ __forceinline__ f32x4 mfma_bf16(bf16x8 a, bf16x8 b, f32x4 c) {
    return __builtin_amdgcn_mfma_f32_16x16x32_bf16(a, b, c, 0, 0, 0);
}

// Load a wave-uniform 128-byte row (32 floats) into SGPRs via scalar pipe.
__device__ __forceinline__ void sload_row128(const float* p, u32x4* r) {
    asm volatile(
        "s_load_dwordx4 %0, %8, 0x0\n"
        "s_load_dwordx4 %1, %8, 0x10\n"
        "s_load_dwordx4 %2, %8, 0x20\n"
        "s_load_dwordx4 %3, %8, 0x30\n"
        "s_load_dwordx4 %4, %8, 0x40\n"
        "s_load_dwordx4 %5, %8, 0x50\n"
        "s_load_dwordx4 %6, %8, 0x60\n"
        "s_load_dwordx4 %7, %8, 0x70\n"
        "s_waitcnt lgkmcnt(0)\n"
        : "=&s"(r[0]), "=&s"(r[1]), "=&s"(r[2]), "=&s"(r[3]),
          "=&s"(r[4]), "=&s"(r[5]), "=&s"(r[6]), "=&s"(r[7])
        : "s"(p));
}

// ---------------------------------------------------------------------------
// Weight prep: W fp32 [K,N] (blockIdx.z batches mats) -> transposed bf16 hi/lo
// [N][K] so GEMM B-frags are k-contiguous.
// ---------------------------------------------------------------------------
__global__ void conv_wt(const float* __restrict__ W, u16* __restrict__ oh,
                        u16* __restrict__ ol, int K, int N)
{
    const long z = blockIdx.z;
    const int idx = blockIdx.x * 256 + threadIdx.x;
    if (idx >= K * N) return;
    const int k = idx / N, n = idx - k * N;
    const float x = W[z * K * N + idx];
    const u16 h = f2bf(x);
    const u16 l = f2bf(x - bf2f(h));
    oh[z * (long)K * N + (long)n * K + k] = h;
    ol[z * (long)K * N + (long)n * K + k] = l;
}

// ---------------------------------------------------------------------------
// bf16x3 MFMA GEMM: C[M,N] = (Ah+Al)[M,K] @ (Bh+Bl)[N,K]^T + bias
// Tile 128x192, BK=32, 256 threads = 4 waves stacked on M (wave-tile 32x192).
// EPI 0: fp32 store.  EPI 2: gelu then bf16 hi/lo pair store.
// ---------------------------------------------------------------------------
template<int EPI>
__global__ __launch_bounds__(256, 2) void gemm_mfma(
    const u16* __restrict__ Ah, const u16* __restrict__ Al,
    const u16* __restrict__ Bh, const u16* __restrict__ Bl,
    const float* __restrict__ bias,
    float* __restrict__ C, u16* __restrict__ Ch, u16* __restrict__ Cl,
    int N, int K)
{
    __shared__ u16 Ash[128][32];
    __shared__ u16 Als[128][32];
    __shared__ u16 Bsh[192][32];
    __shared__ u16 Bsl[192][32];
    const int tid = threadIdx.x;
    const int wave = tid >> 6, lane = tid & 63;
    const int lm = lane & 15, quad = lane >> 4;
    const long m0 = (long)blockIdx.x * 128;
    const int n0 = blockIdx.y * 192;

    const int ra = tid >> 1, rk = (tid & 1) * 16;
    const u16* pAh = Ah + (m0 + ra) * K + rk;
    const u16* pAl = Al + (m0 + ra) * K + rk;
    const int b0r = tid >> 1, b0k = (tid & 1) * 16;
    const int b1r = b0r + 128;
    const u16* pBh0 = Bh + (long)(n0 + b0r) * K + b0k;
    const u16* pBl0 = Bl + (long)(n0 + b0r) * K + b0k;
    const u16* pBh1 = Bh + (long)(n0 + b1r) * K + b0k;
    const u16* pBl1 = Bl + (long)(n0 + b1r) * K + b0k;
    const bool hasB1 = (tid < 128);

    f32x4 acc[2][12];
#pragma unroll
    for (int i = 0; i < 2; i++)
#pragma unroll
        for (int j = 0; j < 12; j++)
#pragma unroll
            for (int r = 0; r < 4; r++) acc[i][j][r] = 0.f;

    uint4 tA0, tA1, tA2, tA3;
    uint4 tB0[4], tB1[4];

#define LOAD_TILES(k0)                                                  \
    do {                                                                \
        tA0 = *(const uint4*)(pAh + (k0));                              \
        tA1 = *(const uint4*)(pAh + (k0) + 8);                          \
        tA2 = *(const uint4*)(pAl + (k0));                              \
        tA3 = *(const uint4*)(pAl + (k0) + 8);                          \
        tB0[0] = *(const uint4*)(pBh0 + (k0));                          \
        tB0[1] = *(const uint4*)(pBh0 + (k0) + 8);                      \
        tB0[2] = *(const uint4*)(pBl0 + (k0));                          \
        tB0[3] = *(const uint4*)(pBl0 + (k0) + 8);                      \
        if (hasB1) {                                                    \
            tB1[0] = *(const uint4*)(pBh1 + (k0));                      \
            tB1[1] = *(const uint4*)(pBh1 + (k0) + 8);                  \
            tB1[2] = *(const uint4*)(pBl1 + (k0));                      \
            tB1[3] = *(const uint4*)(pBl1 + (k0) + 8);                  \
        }                                                               \
    } while (0)

#define STORE_TILES()                                                   \
    do {                                                                \
        *(uint4*)&Ash[ra][rk] = tA0;                                    \
        *(uint4*)&Ash[ra][rk + 8] = tA1;                                \
        *(uint4*)&Als[ra][rk] = tA2;                                    \
        *(uint4*)&Als[ra][rk + 8] = tA3;                                \
        *(uint4*)&Bsh[b0r][b0k] = tB0[0];                               \
        *(uint4*)&Bsh[b0r][b0k + 8] = tB0[1];                           \
        *(uint4*)&Bsl[b0r][b0k] = tB0[2];                               \
        *(uint4*)&Bsl[b0r][b0k + 8] = tB0[3];                           \
        if (hasB1) {                                                    \
            *(uint4*)&Bsh[b1r][b0k] = tB1[0];                           \
            *(uint4*)&Bsh[b1r][b0k + 8] = tB1[1];                       \
            *(uint4*)&Bsl[b1r][b0k] = tB1[2];                           \
            *(uint4*)&Bsl[b1r][b0k + 8] = tB1[3];                       \
        }                                                               \
    } while (0)

    const int kt = K >> 5;
    LOAD_TILES(0);
    STORE_TILES();
    __syncthreads();

    for (int t = 0; t < kt; t++) {
        if (t + 1 < kt) LOAD_TILES((t + 1) << 5);

        bf16x8 afh[2], afl[2];
#pragma unroll
        for (int mi = 0; mi < 2; mi++) {
            afh[mi] = *(const bf16x8*)&Ash[wave * 32 + mi * 16 + lm][quad * 8];
            afl[mi] = *(const bf16x8*)&Als[wave * 32 + mi * 16 + lm][quad * 8];
        }
#pragma unroll
        for (int g = 0; g < 4; g++) {
            bf16x8 bfh[3], bfl[3];
#pragma unroll
            for (int j = 0; j < 3; j++) {
                bfh[j] = *(const bf16x8*)&Bsh[g * 48 + j * 16 + lm][quad * 8];
                bfl[j] = *(const bf16x8*)&Bsl[g * 48 + j * 16 + lm][quad * 8];
            }
#pragma unroll
            for (int mi = 0; mi < 2; mi++)
#pragma unroll
                for (int j = 0; j < 3; j++) {
                    const int ni = g * 3 + j;
                    acc[mi][ni] = mfma_bf16(afh[mi], bfh[j], acc[mi][ni]);
                    acc[mi][ni] = mfma_bf16(afh[mi], bfl[j], acc[mi][ni]);
                    acc[mi][ni] = mfma_bf16(afl[mi], bfh[j], acc[mi][ni]);
                }
        }
        if (t + 1 < kt) {
            __syncthreads();
            STORE_TILES();
            __syncthreads();
        }
    }

    // epilogue: C/D layout col = lane&15, row = quad*4 + r
#pragma unroll
    for (int mi = 0; mi < 2; mi++) {
        const long rowb = m0 + wave * 32 + mi * 16 + quad * 4;
#pragma unroll
        for (int ni = 0; ni < 12; ni++) {
            const int col = n0 + ni * 16 + lm;
            const float bv = bias[col];
#pragma unroll
            for (int r = 0; r < 4; r++) {
                float v = acc[mi][ni][r] + bv;
                if (EPI == 2) {
                    v = gelu_exact(v);
                    const u16 h = f2bf(v);
                    const u16 l = f2bf(v - bf2f(h));
                    Ch[(rowb + r) * N + col] = h;
                    Cl[(rowb + r) * N + col] = l;
                } else {
                    C[(rowb + r) * N + col] = v;
                }
            }
        }
    }
#undef LOAD_TILES
#undef STORE_TILES
}

// ---------------------------------------------------------------------------
// fp32 GEMM (tokenizer batched + tiny pool GEMMs). Tile 128x64, BK=16.
// ---------------------------------------------------------------------------
template<int EPI, bool SPLIT>
__global__ __launch_bounds__(256) void gemm_kernel(
    const float* __restrict__ A, int lda, long strideA,
    const float* __restrict__ Bw, long strideB,
    const float* __restrict__ bias, long strideBias,
    float* __restrict__ C, int ldc, long strideC,
    int M, int N, int K, int ldb)
{
    __shared__ float As[16][132];
    __shared__ float Bs[16][68];

    const int z = blockIdx.z;
    const float* Ab    = A    + (long)z * strideA;
    const float* Bb    = Bw   + (long)z * strideB;
    const float* biasb = bias + (long)z * strideBias;
    float*       Cb    = C    + (long)z * strideC;

    const int row0 = blockIdx.x * 128;
    const int col0 = blockIdx.y * 64;
    const int tid  = threadIdx.x;
    const int tm = tid >> 4;
    const int tn = tid & 15;

    const int la_m = tid >> 1;
    const int la_k = (tid & 1) * 8;
    const int lb_k = tid >> 4;
    const int lb_n = (tid & 15) * 4;

    const float* bcol = Bb + (col0 + lb_n);
    const float* arow = Ab + (long)(row0 + la_m) * lda;
    const bool vecA = ((lda & 3) == 0) &&
                      ((((unsigned long long)(const void*)arow) & 15ull) == 0ull);

    float acc[8][4];
#pragma unroll
    for (int i = 0; i < 8; i++)
#pragma unroll
        for (int j = 0; j < 4; j++) acc[i][j] = 0.f;

    for (int k0 = 0; k0 < K; k0 += 16) {
        if (vecA && (k0 + 16 <= K)) {
            float4 v0 = *(const float4*)(arow + k0 + la_k);
            float4 v1 = *(const float4*)(arow + k0 + la_k + 4);
            As[la_k + 0][la_m] = v0.x; As[la_k + 1][la_m] = v0.y;
            As[la_k + 2][la_m] = v0.z; As[la_k + 3][la_m] = v0.w;
            As[la_k + 4][la_m] = v1.x; As[la_k + 5][la_m] = v1.y;
            As[la_k + 6][la_m] = v1.z; As[la_k + 7][la_m] = v1.w;
        } else {
#pragma unroll
            for (int i = 0; i < 8; i++) {
                int k = k0 + la_k + i;
                As[la_k + i][la_m] = (k < K) ? arow[k] : 0.f;
            }
        }
        {
            int k = k0 + lb_k;
            float4 v = make_float4(0.f, 0.f, 0.f, 0.f);
            if (k < K) v = *(const float4*)(bcol + (long)k * ldb);
            *(float4*)&Bs[lb_k][lb_n] = v;
        }
        __syncthreads();
#pragma unroll
        for (int kk = 0; kk < 16; kk++) {
            float4 a0 = *(const float4*)&As[kk][tm * 8];
            float4 a1 = *(const float4*)&As[kk][tm * 8 + 4];
            float4 b4 = *(const float4*)&Bs[kk][tn * 4];
            float av[8] = {a0.x, a0.y, a0.z, a0.w, a1.x, a1.y, a1.z, a1.w};
            float bv[4] = {b4.x, b4.y, b4.z, b4.w};
#pragma unroll
            for (int i = 0; i < 8; i++)
#pragma unroll
                for (int j = 0; j < 4; j++) acc[i][j] += av[i] * bv[j];
        }
        __syncthreads();
    }

    const int gcol = col0 + tn * 4;
    float4 bv4 = *(const float4*)(biasb + gcol);
#pragma unroll
    for (int i = 0; i < 8; i++) {
        int grow = row0 + tm * 8 + i;
        float4 o;
        o.x = acc[i][0] + bv4.x; o.y = acc[i][1] + bv4.y;
        o.z = acc[i][2] + bv4.z; o.w = acc[i][3] + bv4.w;
        if (EPI == 1) {
            o.x = gelu_exact(o.x); o.y = gelu_exact(o.y);
            o.z = gelu_exact(o.z); o.w = gelu_exact(o.w);
        }
        *(float4*)(Cb + (long)grow * ldc + gcol) = o;
    }
}

// ---------------------------------------------------------------------------
// tokenizer post: h = gelu(LN(src; g[r],b[r])) + pos[r] -> bf16 hi/lo pair
// ---------------------------------------------------------------------------
__global__ __launch_bounds__(64) void tok_ln_pair(
    const float* __restrict__ src, u16* __restrict__ hh, u16* __restrict__ hl,
    const float* __restrict__ g, const float* __restrict__ bt,
    const float* __restrict__ pos)
{
    const long row = blockIdx.x;
    const int r = (int)(row % 200);
    const int l = threadIdx.x;
    const float* sp = src + row * 192;
    float x0 = sp[l], x1 = sp[l + 64], x2 = sp[l + 128];
    float m = wave_sum(x0 + x1 + x2) * (1.f / 192.f);
    float d0 = x0 - m, d1 = x1 - m, d2 = x2 - m;
    float v = wave_sum(d0 * d0 + d1 * d1 + d2 * d2) * (1.f / 192.f);
    float rs = 1.f / sqrtf(v + 1e-5f);
    const float* gr = g + r * 192;
    const float* br = bt + r * 192;
    const float* pr = pos + r * 192;
    const long base = row * 192;
#pragma unroll
    for (int i = 0; i < 3; i++) {
        const int c = l + 64 * i;
        const float d = (i == 0) ? d0 : (i == 1) ? d1 : d2;
        const float y = gelu_exact(d * rs * gr[c] + br[c]) + pr[c];
        const u16 h = f2bf(y);
        hh[base + c] = h;
        hl[base + c] = f2bf(y - bf2f(h));
    }
}

// ---------------------------------------------------------------------------
// h = LN((hh+hl) + a; g, b) -> pair, in place.
// ---------------------------------------------------------------------------
__global__ __launch_bounds__(64) void resid_ln_pair(
    u16* __restrict__ hh, u16* __restrict__ hl, const float* __restrict__ a,
    const float* __restrict__ g, const float* __restrict__ bt)
{
    const long row = blockIdx.x;
    const int l = threadIdx.x;
    const long base = row * 192;
    float x0 = bf2f(hh[base + l])       + bf2f(hl[base + l])       + a[base + l];
    float x1 = bf2f(hh[base + l + 64])  + bf2f(hl[base + l + 64])  + a[base + l + 64];
    float x2 = bf2f(hh[base + l + 128]) + bf2f(hl[base + l + 128]) + a[base + l + 128];
    float m = wave_sum(x0 + x1 + x2) * (1.f / 192.f);
    float d0 = x0 - m, d1 = x1 - m, d2 = x2 - m;
    float v = wave_sum(d0 * d0 + d1 * d1 + d2 * d2) * (1.f / 192.f);
    float rs = 1.f / sqrtf(v + 1e-5f);
#pragma unroll
    for (int i = 0; i < 3; i++) {
        const int c = l + 64 * i;
        const float d = (i == 0) ? d0 : (i == 1) ? d1 : d2;
        const float y = d * rs * g[c] + bt[c];
        const u16 h = f2bf(y);
        hh[base + c] = h;
        hl[base + c] = f2bf(y - bf2f(h));
    }
}

// ---------------------------------------------------------------------------
// Encoder self-attention v3: K/V rows via scalar s_load (SGPRs), pure-VALU
// inner loop. Lanes = queries (256 slots, 200 live). No LDS, no VMEM in loop.
// qkv: [T,576] fp32; out pair: [T,192].
// ---------------------------------------------------------------------------
__global__ __launch_bounds__(256) void attn_enc(
    const float* __restrict__ qkv, u16* __restrict__ outh, u16* __restrict__ outl)
{
    const int bh = blockIdx.x;
    const int b = bh / 6, h = bh % 6;
    const int tid = threadIdx.x;
    const int q = tid;
    const int qc = (q < 200) ? q : 199;

    const float* qrow = qkv + (long)(b * 200 + qc) * 576 + h * 32;
    float qr[32];
#pragma unroll
    for (int u = 0; u < 8; u++) {
        float4 t = *(const float4*)(qrow + 4 * u);
        qr[4 * u] = t.x; qr[4 * u + 1] = t.y;
        qr[4 * u + 2] = t.z; qr[4 * u + 3] = t.w;
    }

    const float scale = 0.17677669529663688f;   // 1/sqrt(32)
    float m = -1e30f, l = 0.f;
    float o[32];
#pragma unroll
    for (int d = 0; d < 32; d++) o[d] = 0.f;

    const float* kbase = qkv + (long)(b * 200) * 576 + 192 + h * 32;
    const float* vbase = kbase + 192;

    for (int j0 = 0; j0 < 200; j0 += 8) {
        float s[8];
        const float* kp = kbase + (long)j0 * 576;
#pragma unroll
        for (int jj = 0; jj < 8; jj++) {
            u32x4 r[8];
            sload_row128(kp, r);
            float acc = 0.f;
#pragma unroll
            for (int g = 0; g < 8; g++) {
                acc = fmaf(qr[4 * g + 0], uf(r[g][0]), acc);
                acc = fmaf(qr[4 * g + 1], uf(r[g][1]), acc);
                acc = fmaf(qr[4 * g + 2], uf(r[g][2]), acc);
                acc = fmaf(qr[4 * g + 3], uf(r[g][3]), acc);
            }
            s[jj] = acc * scale;
            kp += 576;
        }
        float cm = m;
#pragma unroll
        for (int jj = 0; jj < 8; jj++) cm = fmaxf(cm, s[jj]);
        float fac = __expf(m - cm);
        m = cm;
        l *= fac;
#pragma unroll
        for (int d = 0; d < 32; d++) o[d] *= fac;
        const float* vp = vbase + (long)j0 * 576;
#pragma unroll
        for (int jj = 0; jj < 8; jj++) {
            u32x4 r[8];
            sload_row128(vp, r);
            float e = __expf(s[jj] - m);
            l += e;
#pragma unroll
            for (int g = 0; g < 8; g++) {
                o[4 * g + 0] = fmaf(e, uf(r[g][0]), o[4 * g + 0]);
                o[4 * g + 1] = fmaf(e, uf(r[g][1]), o[4 * g + 1]);
                o[4 * g + 2] = fmaf(e, uf(r[g][2]), o[4 * g + 2]);
                o[4 * g + 3] = fmaf(e, uf(r[g][3]), o[4 * g + 3]);
            }
            vp += 576;
        }
    }
    const float inv = 1.f / l;
    if (q < 200) {
        const long ob = (long)(b * 200 + q) * 192 + h * 32;
#pragma unroll
        for (int u = 0; u < 16; u++) {
            const float v0 = o[2 * u] * inv, v1 = o[2 * u + 1] * inv;
            const u16 h0 = f2bf(v0), h1 = f2bf(v1);
            const u16 l0 = f2bf(v0 - bf2f(h0)), l1 = f2bf(v1 - bf2f(h1));
            *(u32*)&outh[ob + 2 * u] = (u32)h0 | ((u32)h1 << 16);
            *(u32*)&outl[ob + 2 * u] = (u32)l0 | ((u32)l1 << 16);
        }
    }
}

// ---------------------------------------------------------------------------
__global__ __launch_bounds__(192) void mean_tokens_pair(
    const u16* __restrict__ hh, const u16* __restrict__ hl, float* __restrict__ qmean)
{
    const int b = blockIdx.x, d = threadIdx.x;
    float s = 0.f;
    for (int r = 0; r < 200; r++) {
        const long idx = ((long)b * 200 + r) * 192 + d;
        s += bf2f(hh[idx]) + bf2f(hl[idx]);
    }
    qmean[b * 192 + d] = s * (1.f / 200.f);
}

// ---------------------------------------------------------------------------
// Pooling attention (fp32): qp [256,192], kv [T,384], out [256,192]
// ---------------------------------------------------------------------------
__global__ __launch_bounds__(64) void attn_pool(
    const float* __restrict__ qp, const float* __restrict__ kv,
    float* __restrict__ out)
{
    __shared__ float p[200];
    const int b = blockIdx.x / 6, h = blockIdx.x % 6;
    const int lane = threadIdx.x;

    const float* qrow = qp + b * 192 + h * 32;
    float qr[32];
#pragma unroll
    for (int u = 0; u < 8; u++) {
        float4 t = *(const float4*)(qrow + 4 * u);
        qr[4 * u] = t.x; qr[4 * u + 1] = t.y;
        qr[4 * u + 2] = t.z; qr[4 * u + 3] = t.w;
    }
    const float scale = 0.17677669529663688f;
    const float* kb = kv + (long)(b * 200) * 384 + h * 32;
    float s[4];
    float mymax = -1e30f;
#pragma unroll
    for (int g = 0; g < 4; g++) {
        int j = lane + 64 * g;
        if (j < 200) {
            const float* kr = kb + (long)j * 384;
            float acc = 0.f;
#pragma unroll
            for (int u = 0; u < 8; u++) {
                float4 k4 = *(const float4*)(kr + 4 * u);
                acc += qr[4 * u] * k4.x + qr[4 * u + 1] * k4.y +
                       qr[4 * u + 2] * k4.z + qr[4 * u + 3] * k4.w;
            }
            s[g] = acc * scale;
            mymax = fmaxf(mymax, s[g]);
        } else {
            s[g] = -1e30f;
        }
    }
    float mx = wave_max(mymax);
    float psum = 0.f;
#pragma unroll
    for (int g = 0; g < 4; g++) {
        int j = lane + 64 * g;
        if (j < 200) {
            float e = __expf(s[g] - mx);
            p[j] = e;
            psum += e;
        }
    }
    float tot = wave_sum(psum);
    __syncthreads();
    const int half = lane >> 5, d = lane & 31;
    const float* vb = kv + (long)(b * 200) * 384 + 192 + h * 32 + d;
    float acc = 0.f;
    for (int jj = 0; jj < 100; jj++) {
        int j = half * 100 + jj;
        acc += p[j] * vb[(long)j * 384];
    }
    acc += __shfl_xor(acc, 32, 64);
    acc /= tot;
    if (lane < 32) out[b * 192 + h * 32 + d] = acc;
}

// ---------------------------------------------------------------------------
__global__ __launch_bounds__(64) void classifier_kernel(
    const float* __restrict__ pooled,
    const float* __restrict__ g, const float* __restrict__ bt,
    const float* __restrict__ W1, const float* __restrict__ b1,
    const float* __restrict__ W2, const float* __restrict__ b2,
    const float* __restrict__ W3, const float* __restrict__ b3,
    float* __restrict__ out)
{
    __shared__ float z[192];
    __shared__ float z1[96];
    __shared__ float z2[48];
    const int b = blockIdx.x, lane = threadIdx.x;
    const float* pr = pooled + b * 192;
    float x0 = pr[lane], x1 = pr[lane + 64], x2 = pr[lane + 128];
    float m = wave_sum(x0 + x1 + x2) * (1.f / 192.f);
    float d0 = x0 - m, d1 = x1 - m, d2 = x2 - m;
    float v = wave_sum(d0 * d0 + d1 * d1 + d2 * d2) * (1.f / 192.f);
    float rs = 1.f / sqrtf(v + 1e-5f);
    z[lane]       = d0 * rs * g[lane]       + bt[lane];
    z[lane + 64]  = d1 * rs * g[lane + 64]  + bt[lane + 64];
    z[lane + 128] = d2 * rs * g[lane + 128] + bt[lane + 128];
    __syncthreads();
#pragma unroll
    for (int rep = 0; rep < 2; rep++) {
        int j = lane + rep * 64;
        if (j < 96) {
            float a = b1[j];
            for (int k = 0; k < 192; k++) a += z[k] * W1[k * 96 + j];
            z1[j] = gelu_exact(a);
        }
    }
    __syncthreads();
    if (lane < 48) {
        float a = b2[lane];
        for (int k = 0; k < 96; k++) a += z1[k] * W2[k * 48 + lane];
        z2[lane] = gelu_exact(a);
    }
    __syncthreads();
    if (lane < 2) {
        float a = b3[lane];
        for (int k = 0; k < 48; k++) a += z2[k] * W3[k * 2 + lane];
        out[b * 2 + lane] = a;
    }
}

// ---------------------------------------------------------------------------
extern "C" void kernel_launch(void* const* d_in, const int* in_sizes, int n_in,
                              void* d_out, int out_size, void* d_ws, size_t ws_size,
                              hipStream_t stream)
{
    (void)in_sizes; (void)n_in; (void)out_size; (void)ws_size;

    const float* x         = (const float*)d_in[0];
    const float* roi_W     = (const float*)d_in[1];
    const float* roi_b     = (const float*)d_in[2];
    const float* roi_ln_g  = (const float*)d_in[3];
    const float* roi_ln_b  = (const float*)d_in[4];
    const float* pos_emb   = (const float*)d_in[5];
    const float* enc_Wqkv  = (const float*)d_in[6];
    const float* enc_bqkv  = (const float*)d_in[7];
    const float* enc_Wo    = (const float*)d_in[8];
    const float* enc_bo    = (const float*)d_in[9];
    const float* enc_ln1_g = (const float*)d_in[10];
    const float* enc_ln1_b = (const float*)d_in[11];
    const float* enc_W1    = (const float*)d_in[12];
    const float* enc_b1    = (const float*)d_in[13];
    const float* enc_W2    = (const float*)d_in[14];
    const float* enc_b2    = (const float*)d_in[15];
    const float* enc_ln2_g = (const float*)d_in[16];
    const float* enc_ln2_b = (const float*)d_in[17];
    const float* pool_Wqkv = (const float*)d_in[18];
    const float* pool_bqkv = (const float*)d_in[19];
    const float* pool_Wo   = (const float*)d_in[20];
    const float* pool_bo   = (const float*)d_in[21];
    const float* cls_ln_g  = (const float*)d_in[22];
    const float* cls_ln_b  = (const float*)d_in[23];
    const float* cls_W1    = (const float*)d_in[24];
    const float* cls_b1    = (const float*)d_in[25];
    const float* cls_W2    = (const float*)d_in[26];
    const float* cls_b2    = (const float*)d_in[27];
    const float* cls_W3    = (const float*)d_in[28];
    const float* cls_b3    = (const float*)d_in[29];

    char* ws = (char*)d_ws;
    u16*   hh    = (u16*)(ws);                      // 19,660,800 B
    u16*   hl    = (u16*)(ws + 19660800);           // 19,660,800 B
    char*  bufA  = ws + 39321600;                   // 117,964,800 B
    float* bufAf = (float*)bufA;
    u16*   ffh   = (u16*)bufA;                      // [T,576] bf16 hi
    u16*   ffl   = (u16*)(bufA + 58982400);         // [T,576] bf16 lo
    char*  bufB  = ws + 157286400;                  // 39,321,600 B
    u16*   bBh   = (u16*)bufB;
    u16*   bBl   = (u16*)(bufB + 19660800);
    float* bufBf = (float*)bufB;
    float* qmean = (float*)(ws + 196608000);
    float* qp    = qmean + 49152;
    float* pattn = qp + 49152;
    float* pooled= pattn + 49152;
    char*  wts   = ws + 197394432;
    u16* WqkvH = (u16*)(wts);                 // 3*576*192
    u16* WqkvL = (u16*)(wts + 663552);
    u16* Wff1H = (u16*)(wts + 1327104);       // 3*576*192
    u16* Wff1L = (u16*)(wts + 1990656);
    u16* Wff2H = (u16*)(wts + 2654208);       // 3*192*576
    u16* Wff2L = (u16*)(wts + 3317760);
    u16* WwoH  = (u16*)(wts + 3981312);       // 3*192*192
    u16* WwoL  = (u16*)(wts + 4202496);
    u16* WkvH  = (u16*)(wts + 4423680);       // 384*192
    u16* WkvL  = (u16*)(wts + 4571136);

    // ---- weight split/transpose (once per call) ----
    conv_wt<<<dim3(144, 1, 9), 256, 0, stream>>>(enc_Wqkv, WqkvH, WqkvL, 192, 192);
    conv_wt<<<dim3(432, 1, 3), 256, 0, stream>>>(enc_W1, Wff1H, Wff1L, 192, 576);
    conv_wt<<<dim3(432, 1, 3), 256, 0, stream>>>(enc_W2, Wff2H, Wff2L, 576, 192);
    conv_wt<<<dim3(144, 1, 3), 256, 0, stream>>>(enc_Wo, WwoH, WwoL, 192, 192);
    conv_wt<<<dim3(144, 1, 2), 256, 0, stream>>>(pool_Wqkv + 36864, WkvH, WkvL, 192, 192);

    // ---- tokenizer (fp32) -> bufAf [T,192] ----
    gemm_kernel<0, false><<<dim3(2, 3, 200), 256, 0, stream>>>(
        x, 39800, 199, roi_W, (long)199 * 192, roi_b, 192,
        bufAf, 38400, 192, 256, 192, 199, 192);
    tok_ln_pair<<<51200, 64, 0, stream>>>(bufAf, hh, hl, roi_ln_g, roi_ln_b, pos_emb);

    // ---- encoder layers ----
    for (int i = 0; i < 3; i++) {
        gemm_mfma<0><<<dim3(400, 3), 256, 0, stream>>>(
            hh, hl, WqkvH + (long)i * 110592, WqkvL + (long)i * 110592,
            enc_bqkv + i * 576, bufAf, nullptr, nullptr, 576, 192);
        attn_enc<<<1536, 256, 0, stream>>>(bufAf, bBh, bBl);
        gemm_mfma<0><<<dim3(400, 1), 256, 0, stream>>>(
            bBh, bBl, WwoH + (long)i * 36864, WwoL + (long)i * 36864,
            enc_bo + i * 192, bufAf, nullptr, nullptr, 192, 192);
        resid_ln_pair<<<51200, 64, 0, stream>>>(hh, hl, bufAf,
            enc_ln1_g + i * 192, enc_ln1_b + i * 192);
        gemm_mfma<2><<<dim3(400, 3), 256, 0, stream>>>(
            hh, hl, Wff1H + (long)i * 110592, Wff1L + (long)i * 110592,
            enc_b1 + i * 576, nullptr, ffh, ffl, 576, 192);
        gemm_mfma<0><<<dim3(400, 1), 256, 0, stream>>>(
            ffh, ffl, Wff2H + (long)i * 110592, Wff2L + (long)i * 110592,
            enc_b2 + i * 192, bufBf, nullptr, nullptr, 192, 576);
        resid_ln_pair<<<51200, 64, 0, stream>>>(hh, hl, bufBf,
            enc_ln2_g + i * 192, enc_ln2_b + i * 192);
    }

    // ---- pooling ----
    mean_tokens_pair<<<256, 192, 0, stream>>>(hh, hl, qmean);
    gemm_kernel<0, false><<<dim3(2, 3, 1), 256, 0, stream>>>(
        qmean, 192, 0, pool_Wqkv, 0, pool_bqkv, 0, qp, 192, 0, 256, 192, 192, 192);
    gemm_mfma<0><<<dim3(400, 2), 256, 0, stream>>>(
        hh, hl, WkvH, WkvL, pool_bqkv + 192, bufAf, nullptr, nullptr, 384, 192);
    attn_pool<<<1536, 64, 0, stream>>>(qp, bufAf, pattn);
    gemm_kernel<0, false><<<dim3(2, 3, 1), 256, 0, stream>>>(
        pattn, 192, 0, pool_Wo, 0, pool_bo, 0, pooled, 192, 0, 256, 192, 192, 192);

    // ---- classifier ----
    classifier_kernel<<<256, 64, 0, stream>>>(
        pooled, cls_ln_g, cls_ln_b,
        cls_W1, cls_b1, cls_W2, cls_b2, cls_W3, cls_b3,
        (float*)d_out);
}

// Round 5
// 1887.502 us; speedup vs baseline: 1.4782x; 1.4782x over previous
//
#include <hip/hip_runtime.h>
#include <math.h>

// B=256, N_ROIS=200, ROI_DIM=199, D=192, H=6, Dh=32, L=3, FF=576, NCLS=2
// T = 51200 tokens.
// GEMMs: bf16x3 split-precision MFMA (Ah*Bh + Ah*Bl + Al*Bh, fp32 accum).
// Attention: MFMA flash (QK^T and PV via 16x16x32 bf16 MFMA, hi/lo split),
// 3 key-phases with online softmax, P transposed C->A layout via packed LDS.

typedef unsigned short u16;
typedef unsigned int u32;
typedef __attribute__((ext_vector_type(8))) __bf16 bf16x8;
typedef __attribute__((ext_vector_type(4))) float f32x4;

__device__ __forceinline__ u16 f2bf(float x) {
    u32 u = __float_as_uint(x);
    u = (u + 0x7FFFu + ((u >> 16) & 1u)) >> 16;   // RNE
    return (u16)u;
}
__device__ __forceinline__ float bf2f(u16 h) {
    return __uint_as_float(((u32)h) << 16);
}

__device__ __forceinline__ float gelu_exact(float x) {
    return 0.5f * x * (1.0f + erff(x * 0.7071067811865475f));
}

__device__ __forceinline__ float wave_sum(float v) {
#pragma unroll
    for (int o = 32; o > 0; o >>= 1) v += __shfl_xor(v, o, 64);
    return v;
}
__device__ __forceinline__ float wave_max(float v) {
#pragma unroll
    for (int o = 32; o > 0; o >>= 1) v = fmaxf(v, __shfl_xor(v, o, 64));
    return v;
}

__device__ __forceinline__ f32x4 mfma_bf16(bf16x8 a, bf16x8 b, f32x4 c) {
    return __builtin_amdgcn_mfma_f32_16x16x32_bf16(a, b, c, 0, 0, 0);
}

// ---------------------------------------------------------------------------
// Weight prep: W fp32 [K,N] (blockIdx.z batches) -> transposed bf16 hi/lo [N][K]
// ---------------------------------------------------------------------------
__global__ void conv_wt(const float* __restrict__ W, u16* __restrict__ oh,
                        u16* __restrict__ ol, int K, int N)
{
    const long z = blockIdx.z;
    const int idx = blockIdx.x * 256 + threadIdx.x;
    if (idx >= K * N) return;
    const int k = idx / N, n = idx - k * N;
    const float x = W[z * K * N + idx];
    const u16 h = f2bf(x);
    const u16 l = f2bf(x - bf2f(h));
    oh[z * (long)K * N + (long)n * K + k] = h;
    ol[z * (long)K * N + (long)n * K + k] = l;
}

// ---------------------------------------------------------------------------
// bf16x3 MFMA GEMM: C[M,N] = A[M,K] @ (Bh+Bl)[N,K]^T + bias
// A either pre-split u16 pairs (AF32=false) or fp32 split during staging.
// Tile 128x192, BK=32, 256 threads = 4 waves on M.
// EPI 0: fp32 C.  EPI 2: gelu -> pair.  EPI 3: pair (no gelu).
// ---------------------------------------------------------------------------
template<int EPI, bool AF32>
__global__ __launch_bounds__(256, 2) void gemm_mfma(
    const u16* __restrict__ Ah, const u16* __restrict__ Al,
    const float* __restrict__ Af,
    const u16* __restrict__ Bh, const u16* __restrict__ Bl,
    const float* __restrict__ bias,
    float* __restrict__ C, u16* __restrict__ Ch, u16* __restrict__ Cl,
    int N, int K)
{
    __shared__ u16 Ash[128][32];
    __shared__ u16 Als[128][32];
    __shared__ u16 Bsh[192][32];
    __shared__ u16 Bsl[192][32];
    const int tid = threadIdx.x;
    const int wave = tid >> 6, lane = tid & 63;
    const int lm = lane & 15, quad = lane >> 4;
    const long m0 = (long)blockIdx.x * 128;
    const int n0 = blockIdx.y * 192;

    const int ra = tid >> 1, rk = (tid & 1) * 16;
    const u16* pAh = Ah + (m0 + ra) * K + rk;
    const u16* pAl = Al + (m0 + ra) * K + rk;
    const float* pAf = Af + (m0 + ra) * K + rk;
    const int b0r = tid >> 1, b0k = (tid & 1) * 16;
    const int b1r = b0r + 128;
    const u16* pBh0 = Bh + (long)(n0 + b0r) * K + b0k;
    const u16* pBl0 = Bl + (long)(n0 + b0r) * K + b0k;
    const u16* pBh1 = Bh + (long)(n0 + b1r) * K + b0k;
    const u16* pBl1 = Bl + (long)(n0 + b1r) * K + b0k;
    const bool hasB1 = (tid < 128);

    f32x4 acc[2][12];
#pragma unroll
    for (int i = 0; i < 2; i++)
#pragma unroll
        for (int j = 0; j < 12; j++)
#pragma unroll
            for (int r = 0; r < 4; r++) acc[i][j][r] = 0.f;

    uint4 tA0, tA1, tA2, tA3;
    uint4 tB0[4], tB1[4];

    auto load_tiles = [&](int k0) {
        if (AF32) {
            tA0 = *(const uint4*)(pAf + k0);
            tA1 = *(const uint4*)(pAf + k0 + 4);
            tA2 = *(const uint4*)(pAf + k0 + 8);
            tA3 = *(const uint4*)(pAf + k0 + 12);
        } else {
            tA0 = *(const uint4*)(pAh + k0);
            tA1 = *(const uint4*)(pAh + k0 + 8);
            tA2 = *(const uint4*)(pAl + k0);
            tA3 = *(const uint4*)(pAl + k0 + 8);
        }
        tB0[0] = *(const uint4*)(pBh0 + k0);
        tB0[1] = *(const uint4*)(pBh0 + k0 + 8);
        tB0[2] = *(const uint4*)(pBl0 + k0);
        tB0[3] = *(const uint4*)(pBl0 + k0 + 8);
        if (hasB1) {
            tB1[0] = *(const uint4*)(pBh1 + k0);
            tB1[1] = *(const uint4*)(pBh1 + k0 + 8);
            tB1[2] = *(const uint4*)(pBl1 + k0);
            tB1[3] = *(const uint4*)(pBl1 + k0 + 8);
        }
    };

    auto store_tiles = [&]() {
        if (AF32) {
            u32 fb[16];
            *(uint4*)&fb[0] = tA0; *(uint4*)&fb[4] = tA1;
            *(uint4*)&fb[8] = tA2; *(uint4*)&fb[12] = tA3;
            u32 hw[8], lw[8];
#pragma unroll
            for (int p = 0; p < 8; p++) {
                u32 u0 = fb[2 * p], u1 = fb[2 * p + 1];
                u32 t0 = (u0 + 0x7FFFu + ((u0 >> 16) & 1u)) & 0xFFFF0000u;
                u32 t1 = (u1 + 0x7FFFu + ((u1 >> 16) & 1u)) & 0xFFFF0000u;
                float lo0 = __uint_as_float(u0 - 0) ; // placeholder avoided
                lo0 = __uint_as_float(u0);           // x0
                float x0 = __uint_as_float(u0), x1 = __uint_as_float(u1);
                float l0 = x0 - __uint_as_float(t0);
                float l1 = x1 - __uint_as_float(t1);
                hw[p] = (t0 >> 16) | t1;
                lw[p] = (__float_as_uint(l0) >> 16) |
                        (__float_as_uint(l1) & 0xFFFF0000u);
            }
            *(uint4*)&Ash[ra][rk] = *(uint4*)&hw[0];
            *(uint4*)&Ash[ra][rk + 8] = *(uint4*)&hw[4];
            *(uint4*)&Als[ra][rk] = *(uint4*)&lw[0];
            *(uint4*)&Als[ra][rk + 8] = *(uint4*)&lw[4];
        } else {
            *(uint4*)&Ash[ra][rk] = tA0;
            *(uint4*)&Ash[ra][rk + 8] = tA1;
            *(uint4*)&Als[ra][rk] = tA2;
            *(uint4*)&Als[ra][rk + 8] = tA3;
        }
        *(uint4*)&Bsh[b0r][b0k] = tB0[0];
        *(uint4*)&Bsh[b0r][b0k + 8] = tB0[1];
        *(uint4*)&Bsl[b0r][b0k] = tB0[2];
        *(uint4*)&Bsl[b0r][b0k + 8] = tB0[3];
        if (hasB1) {
            *(uint4*)&Bsh[b1r][b0k] = tB1[0];
            *(uint4*)&Bsh[b1r][b0k + 8] = tB1[1];
            *(uint4*)&Bsl[b1r][b0k] = tB1[2];
            *(uint4*)&Bsl[b1r][b0k + 8] = tB1[3];
        }
    };

    const int kt = K >> 5;
    load_tiles(0);
    store_tiles();
    __syncthreads();

    for (int t = 0; t < kt; t++) {
        if (t + 1 < kt) load_tiles((t + 1) << 5);

        bf16x8 afh[2], afl[2];
#pragma unroll
        for (int mi = 0; mi < 2; mi++) {
            afh[mi] = *(const bf16x8*)&Ash[wave * 32 + mi * 16 + lm][quad * 8];
            afl[mi] = *(const bf16x8*)&Als[wave * 32 + mi * 16 + lm][quad * 8];
        }
#pragma unroll
        for (int g = 0; g < 4; g++) {
            bf16x8 bfh[3], bfl[3];
#pragma unroll
            for (int j = 0; j < 3; j++) {
                bfh[j] = *(const bf16x8*)&Bsh[g * 48 + j * 16 + lm][quad * 8];
                bfl[j] = *(const bf16x8*)&Bsl[g * 48 + j * 16 + lm][quad * 8];
            }
#pragma unroll
            for (int mi = 0; mi < 2; mi++)
#pragma unroll
                for (int j = 0; j < 3; j++) {
                    const int ni = g * 3 + j;
                    acc[mi][ni] = mfma_bf16(afh[mi], bfh[j], acc[mi][ni]);
                    acc[mi][ni] = mfma_bf16(afh[mi], bfl[j], acc[mi][ni]);
                    acc[mi][ni] = mfma_bf16(afl[mi], bfh[j], acc[mi][ni]);
                }
        }
        if (t + 1 < kt) {
            __syncthreads();
            store_tiles();
            __syncthreads();
        }
    }

    // epilogue: C/D layout col = lane&15, row = quad*4 + r
#pragma unroll
    for (int mi = 0; mi < 2; mi++) {
        const long rowb = m0 + wave * 32 + mi * 16 + quad * 4;
#pragma unroll
        for (int ni = 0; ni < 12; ni++) {
            const int col = n0 + ni * 16 + lm;
            const float bv = bias[col];
#pragma unroll
            for (int r = 0; r < 4; r++) {
                float v = acc[mi][ni][r] + bv;
                if (EPI == 0) {
                    C[(rowb + r) * N + col] = v;
                } else {
                    if (EPI == 2) v = gelu_exact(v);
                    const u16 h = f2bf(v);
                    const u16 l = f2bf(v - bf2f(h));
                    Ch[(rowb + r) * N + col] = h;
                    Cl[(rowb + r) * N + col] = l;
                }
            }
        }
    }
}

// ---------------------------------------------------------------------------
// fp32 GEMM (tokenizer batched + tiny pool GEMMs). Tile 128x64, BK=16.
// ---------------------------------------------------------------------------
template<int EPI>
__global__ __launch_bounds__(256) void gemm_kernel(
    const float* __restrict__ A, int lda, long strideA,
    const float* __restrict__ Bw, long strideB,
    const float* __restrict__ bias, long strideBias,
    float* __restrict__ C, int ldc, long strideC,
    int M, int N, int K, int ldb)
{
    __shared__ float As[16][132];
    __shared__ float Bs[16][68];

    const int z = blockIdx.z;
    const float* Ab    = A    + (long)z * strideA;
    const float* Bb    = Bw   + (long)z * strideB;
    const float* biasb = bias + (long)z * strideBias;
    float*       Cb    = C    + (long)z * strideC;

    const int row0 = blockIdx.x * 128;
    const int col0 = blockIdx.y * 64;
    const int tid  = threadIdx.x;
    const int tm = tid >> 4;
    const int tn = tid & 15;

    const int la_m = tid >> 1;
    const int la_k = (tid & 1) * 8;
    const int lb_k = tid >> 4;
    const int lb_n = (tid & 15) * 4;

    const float* bcol = Bb + (col0 + lb_n);
    const float* arow = Ab + (long)(row0 + la_m) * lda;
    const bool vecA = ((lda & 3) == 0) &&
                      ((((unsigned long long)(const void*)arow) & 15ull) == 0ull);

    float acc[8][4];
#pragma unroll
    for (int i = 0; i < 8; i++)
#pragma unroll
        for (int j = 0; j < 4; j++) acc[i][j] = 0.f;

    for (int k0 = 0; k0 < K; k0 += 16) {
        if (vecA && (k0 + 16 <= K)) {
            float4 v0 = *(const float4*)(arow + k0 + la_k);
            float4 v1 = *(const float4*)(arow + k0 + la_k + 4);
            As[la_k + 0][la_m] = v0.x; As[la_k + 1][la_m] = v0.y;
            As[la_k + 2][la_m] = v0.z; As[la_k + 3][la_m] = v0.w;
            As[la_k + 4][la_m] = v1.x; As[la_k + 5][la_m] = v1.y;
            As[la_k + 6][la_m] = v1.z; As[la_k + 7][la_m] = v1.w;
        } else {
#pragma unroll
            for (int i = 0; i < 8; i++) {
                int k = k0 + la_k + i;
                As[la_k + i][la_m] = (k < K) ? arow[k] : 0.f;
            }
        }
        {
            int k = k0 + lb_k;
            float4 v = make_float4(0.f, 0.f, 0.f, 0.f);
            if (k < K) v = *(const float4*)(bcol + (long)k * ldb);
            *(float4*)&Bs[lb_k][lb_n] = v;
        }
        __syncthreads();
#pragma unroll
        for (int kk = 0; kk < 16; kk++) {
            float4 a0 = *(const float4*)&As[kk][tm * 8];
            float4 a1 = *(const float4*)&As[kk][tm * 8 + 4];
            float4 b4 = *(const float4*)&Bs[kk][tn * 4];
            float av[8] = {a0.x, a0.y, a0.z, a0.w, a1.x, a1.y, a1.z, a1.w};
            float bv[4] = {b4.x, b4.y, b4.z, b4.w};
#pragma unroll
            for (int i = 0; i < 8; i++)
#pragma unroll
                for (int j = 0; j < 4; j++) acc[i][j] += av[i] * bv[j];
        }
        __syncthreads();
    }

    const int gcol = col0 + tn * 4;
    float4 bv4 = *(const float4*)(biasb + gcol);
#pragma unroll
    for (int i = 0; i < 8; i++) {
        int grow = row0 + tm * 8 + i;
        float4 o;
        o.x = acc[i][0] + bv4.x; o.y = acc[i][1] + bv4.y;
        o.z = acc[i][2] + bv4.z; o.w = acc[i][3] + bv4.w;
        if (EPI == 1) {
            o.x = gelu_exact(o.x); o.y = gelu_exact(o.y);
            o.z = gelu_exact(o.z); o.w = gelu_exact(o.w);
        }
        *(float4*)(Cb + (long)grow * ldc + gcol) = o;
    }
}

// ---------------------------------------------------------------------------
// tokenizer post: h = gelu(LN(src; g[r],b[r])) + pos[r] -> bf16 hi/lo pair
// ---------------------------------------------------------------------------
__global__ __launch_bounds__(64) void tok_ln_pair(
    const float* __restrict__ src, u16* __restrict__ hh, u16* __restrict__ hl,
    const float* __restrict__ g, const float* __restrict__ bt,
    const float* __restrict__ pos)
{
    const long row = blockIdx.x;
    const int r = (int)(row % 200);
    const int l = threadIdx.x;
    const float* sp = src + row * 192;
    float x0 = sp[l], x1 = sp[l + 64], x2 = sp[l + 128];
    float m = wave_sum(x0 + x1 + x2) * (1.f / 192.f);
    float d0 = x0 - m, d1 = x1 - m, d2 = x2 - m;
    float v = wave_sum(d0 * d0 + d1 * d1 + d2 * d2) * (1.f / 192.f);
    float rs = 1.f / sqrtf(v + 1e-5f);
    const float* gr = g + r * 192;
    const float* br = bt + r * 192;
    const float* pr = pos + r * 192;
    const long base = row * 192;
#pragma unroll
    for (int i = 0; i < 3; i++) {
        const int c = l + 64 * i;
        const float d = (i == 0) ? d0 : (i == 1) ? d1 : d2;
        const float y = gelu_exact(d * rs * gr[c] + br[c]) + pr[c];
        const u16 h = f2bf(y);
        hh[base + c] = h;
        hl[base + c] = f2bf(y - bf2f(h));
    }
}

// ---------------------------------------------------------------------------
// h = LN((hh+hl) + a; g, b) -> pair, in place.
// ---------------------------------------------------------------------------
__global__ __launch_bounds__(64) void resid_ln_pair(
    u16* __restrict__ hh, u16* __restrict__ hl, const float* __restrict__ a,
    const float* __restrict__ g, const float* __restrict__ bt)
{
    const long row = blockIdx.x;
    const int l = threadIdx.x;
    const long base = row * 192;
    float x0 = bf2f(hh[base + l])       + bf2f(hl[base + l])       + a[base + l];
    float x1 = bf2f(hh[base + l + 64])  + bf2f(hl[base + l + 64])  + a[base + l + 64];
    float x2 = bf2f(hh[base + l + 128]) + bf2f(hl[base + l + 128]) + a[base + l + 128];
    float m = wave_sum(x0 + x1 + x2) * (1.f / 192.f);
    float d0 = x0 - m, d1 = x1 - m, d2 = x2 - m;
    float v = wave_sum(d0 * d0 + d1 * d1 + d2 * d2) * (1.f / 192.f);
    float rs = 1.f / sqrtf(v + 1e-5f);
#pragma unroll
    for (int i = 0; i < 3; i++) {
        const int c = l + 64 * i;
        const float d = (i == 0) ? d0 : (i == 1) ? d1 : d2;
        const float y = d * rs * g[c] + bt[c];
        const u16 h = f2bf(y);
        hh[base + c] = h;
        hl[base + c] = f2bf(y - bf2f(h));
    }
}

// ---------------------------------------------------------------------------
// MFMA flash encoder attention. One block per (b,h); 4 waves.
// qkvh/qkvl: [T,576] bf16 pairs (q|k|v, each [6][32]).  out: fp32 [T,192].
// 3 key phases (96/96/8+pad); online softmax; P C->A layout via packed LDS.
// ---------------------------------------------------------------------------
__global__ __launch_bounds__(256, 2) void attn_enc_mfma(
    const u16* __restrict__ qkvh, const u16* __restrict__ qkvl,
    float* __restrict__ out)
{
    __shared__ u16 Ksh[96][40];
    __shared__ u16 Ksl[96][40];
    __shared__ u16 Vth[32][120];
    __shared__ u16 Vtl[32][120];
    __shared__ u32 Pbuf[4][16][108];

    const int bh = blockIdx.x;
    const int b = bh / 6, h = bh % 6;
    const int tid = threadIdx.x;
    const int wave = tid >> 6, lane = tid & 63;
    const int lm = lane & 15, quad = lane >> 4;
    const int nq = (wave == 0) ? 4 : 3;   // q-tiles: wave + 4*i (13 total)

    // ---- Q fragments (A-layout: m=lm, k=quad*8+j) ----
    uint4 qh[4], ql[4];
#pragma unroll
    for (int i = 0; i < 4; i++) {
        if (i < nq) {
            int qt = wave + 4 * i;
            int qrow = qt * 16 + lm; if (qrow > 199) qrow = 199;
            const long off = (long)(b * 200 + qrow) * 576 + h * 32 + quad * 8;
            qh[i] = *(const uint4*)(qkvh + off);
            ql[i] = *(const uint4*)(qkvl + off);
        }
    }

    float mrow[4][4], lrow[4][4];
    f32x4 accO[4][2];
#pragma unroll
    for (int i = 0; i < 4; i++)
#pragma unroll
        for (int r = 0; r < 4; r++) {
            mrow[i][r] = -1e30f; lrow[i][r] = 0.f;
            accO[i][0][r] = 0.f; accO[i][1][r] = 0.f;
        }

    const float scale = 0.17677669529663688f;   // 1/sqrt(32)

#pragma unroll
    for (int ph = 0; ph < 3; ph++) {
        const int base = (ph == 0) ? 0 : (ph == 1) ? 96 : 192;
        const int ntl  = (ph == 2) ? 2 : 6;      // 16-key S tiles
        const int nck  = (ph == 2) ? 1 : 3;      // 32-key PV chunks
        const int nslot = ntl * 16;

        __syncthreads();
        if (tid < nslot) {
            const int key = base + tid;
            const bool valid = key < 200;
            const long roff = (long)(b * 200 + (valid ? key : 0)) * 576 + h * 32;
            uint4 z4 = make_uint4(0, 0, 0, 0);
#pragma unroll
            for (int u = 0; u < 4; u++) {
                uint4 kh = valid ? *(const uint4*)(qkvh + roff + 192 + u * 8) : z4;
                uint4 kl = valid ? *(const uint4*)(qkvl + roff + 192 + u * 8) : z4;
                *(uint4*)&Ksh[tid][u * 8] = kh;
                *(uint4*)&Ksl[tid][u * 8] = kl;
                uint4 vh = valid ? *(const uint4*)(qkvh + roff + 384 + u * 8) : z4;
                uint4 vl = valid ? *(const uint4*)(qkvl + roff + 384 + u * 8) : z4;
                const u16* vhp = (const u16*)&vh;
                const u16* vlp = (const u16*)&vl;
#pragma unroll
                for (int j = 0; j < 8; j++) {
                    Vth[u * 8 + j][tid] = vhp[j];
                    Vtl[u * 8 + j][tid] = vlp[j];
                }
            }
        }
        __syncthreads();

#pragma unroll
        for (int i = 0; i < 4; i++) {
            if (i >= nq) continue;
            const bf16x8 qhf = *(const bf16x8*)&qh[i];
            const bf16x8 qlf = *(const bf16x8*)&ql[i];
            float s[6][4];
#pragma unroll
            for (int ni = 0; ni < 6; ni++) {
                if (ni >= ntl) continue;
                bf16x8 kh8 = *(const bf16x8*)&Ksh[ni * 16 + lm][quad * 8];
                bf16x8 kl8 = *(const bf16x8*)&Ksl[ni * 16 + lm][quad * 8];
                f32x4 c = {0.f, 0.f, 0.f, 0.f};
                c = mfma_bf16(qhf, kh8, c);
                c = mfma_bf16(qhf, kl8, c);
                c = mfma_bf16(qlf, kh8, c);
                const bool masked = (base + ni * 16 + lm) >= 200;
#pragma unroll
                for (int r = 0; r < 4; r++)
                    s[ni][r] = masked ? -1e30f : c[r] * scale;
            }
            // online softmax per row (rows quad*4+r)
            float fac[4];
#pragma unroll
            for (int r = 0; r < 4; r++) {
                float pm = s[0][r];
#pragma unroll
                for (int ni = 1; ni < 6; ni++)
                    if (ni < ntl) pm = fmaxf(pm, s[ni][r]);
                pm = fmaxf(pm, __shfl_xor(pm, 1, 64));
                pm = fmaxf(pm, __shfl_xor(pm, 2, 64));
                pm = fmaxf(pm, __shfl_xor(pm, 4, 64));
                pm = fmaxf(pm, __shfl_xor(pm, 8, 64));
                const float mn = fmaxf(mrow[i][r], pm);
                fac[r] = __expf(mrow[i][r] - mn);
                mrow[i][r] = mn;
                float ps = 0.f;
#pragma unroll
                for (int ni = 0; ni < 6; ni++) {
                    if (ni >= ntl) continue;
                    float e = __expf(s[ni][r] - mn);
                    s[ni][r] = e;
                    ps += e;
                }
                ps += __shfl_xor(ps, 1, 64);
                ps += __shfl_xor(ps, 2, 64);
                ps += __shfl_xor(ps, 4, 64);
                ps += __shfl_xor(ps, 8, 64);
                lrow[i][r] = lrow[i][r] * fac[r] + ps;
                accO[i][0][r] *= fac[r];
                accO[i][1][r] *= fac[r];
            }
            // write P (packed hi|lo) to Pbuf
#pragma unroll
            for (int ni = 0; ni < 6; ni++) {
                if (ni >= ntl) continue;
#pragma unroll
                for (int r = 0; r < 4; r++) {
                    const float e = s[ni][r];
                    const u32 uu = __float_as_uint(e);
                    const u32 t = (uu + 0x7FFFu + ((uu >> 16) & 1u)) & 0xFFFF0000u;
                    const float lo = e - __uint_as_float(t);
                    const u32 pk = t | (__float_as_uint(lo) >> 16);
                    Pbuf[wave][quad * 4 + r][ni * 16 + lm] = pk;
                }
            }
            // PV
#pragma unroll
            for (int ck = 0; ck < 3; ck++) {
                if (ck >= nck) continue;
                uint4 w01 = *(const uint4*)&Pbuf[wave][lm][ck * 32 + quad * 8];
                uint4 w23 = *(const uint4*)&Pbuf[wave][lm][ck * 32 + quad * 8 + 4];
                uint4 hiu, lou;
                hiu.x = __builtin_amdgcn_perm(w01.y, w01.x, 0x07060302u);
                hiu.y = __builtin_amdgcn_perm(w01.w, w01.z, 0x07060302u);
                hiu.z = __builtin_amdgcn_perm(w23.y, w23.x, 0x07060302u);
                hiu.w = __builtin_amdgcn_perm(w23.w, w23.z, 0x07060302u);
                lou.x = __builtin_amdgcn_perm(w01.y, w01.x, 0x05040100u);
                lou.y = __builtin_amdgcn_perm(w01.w, w01.z, 0x05040100u);
                lou.z = __builtin_amdgcn_perm(w23.y, w23.x, 0x05040100u);
                lou.w = __builtin_amdgcn_perm(w23.w, w23.z, 0x05040100u);
                const bf16x8 phf = *(const bf16x8*)&hiu;
                const bf16x8 plf = *(const bf16x8*)&lou;
#pragma unroll
                for (int nt = 0; nt < 2; nt++) {
                    bf16x8 vh8 = *(const bf16x8*)&Vth[nt * 16 + lm][ck * 32 + quad * 8];
                    bf16x8 vl8 = *(const bf16x8*)&Vtl[nt * 16 + lm][ck * 32 + quad * 8];
                    accO[i][nt] = mfma_bf16(phf, vh8, accO[i][nt]);
                    accO[i][nt] = mfma_bf16(plf, vh8, accO[i][nt]);
                    accO[i][nt] = mfma_bf16(phf, vl8, accO[i][nt]);
                }
            }
        }
    }

    // epilogue: O row = qt*16 + quad*4 + r, col = h*32 + nt*16 + lm
#pragma unroll
    for (int i = 0; i < 4; i++) {
        if (i >= nq) continue;
        const int qt = wave + 4 * i;
#pragma unroll
        for (int r = 0; r < 4; r++) {
            const int qrow = qt * 16 + quad * 4 + r;
            if (qrow >= 200) continue;
            const float inv = 1.f / lrow[i][r];
            float* op = out + (long)(b * 200 + qrow) * 192 + h * 32 + lm;
            op[0]  = accO[i][0][r] * inv;
            op[16] = accO[i][1][r] * inv;
        }
    }
}

// ---------------------------------------------------------------------------
__global__ __launch_bounds__(192) void mean_tokens_pair(
    const u16* __restrict__ hh, const u16* __restrict__ hl, float* __restrict__ qmean)
{
    const int b = blockIdx.x, d = threadIdx.x;
    float s = 0.f;
    for (int r = 0; r < 200; r++) {
        const long idx = ((long)b * 200 + r) * 192 + d;
        s += bf2f(hh[idx]) + bf2f(hl[idx]);
    }
    qmean[b * 192 + d] = s * (1.f / 200.f);
}

// ---------------------------------------------------------------------------
// Pooling attention (fp32): qp [256,192], kv [T,384], out [256,192]
// ---------------------------------------------------------------------------
__global__ __launch_bounds__(64) void attn_pool(
    const float* __restrict__ qp, const float* __restrict__ kv,
    float* __restrict__ out)
{
    __shared__ float p[200];
    const int b = blockIdx.x / 6, h = blockIdx.x % 6;
    const int lane = threadIdx.x;

    const float* qrow = qp + b * 192 + h * 32;
    float qr[32];
#pragma unroll
    for (int u = 0; u < 8; u++) {
        float4 t = *(const float4*)(qrow + 4 * u);
        qr[4 * u] = t.x; qr[4 * u + 1] = t.y;
        qr[4 * u + 2] = t.z; qr[4 * u + 3] = t.w;
    }
    const float scale = 0.17677669529663688f;
    const float* kb = kv + (long)(b * 200) * 384 + h * 32;
    float s[4];
    float mymax = -1e30f;
#pragma unroll
    for (int g = 0; g < 4; g++) {
        int j = lane + 64 * g;
        if (j < 200) {
            const float* kr = kb + (long)j * 384;
            float acc = 0.f;
#pragma unroll
            for (int u = 0; u < 8; u++) {
                float4 k4 = *(const float4*)(kr + 4 * u);
                acc += qr[4 * u] * k4.x + qr[4 * u + 1] * k4.y +
                       qr[4 * u + 2] * k4.z + qr[4 * u + 3] * k4.w;
            }
            s[g] = acc * scale;
            mymax = fmaxf(mymax, s[g]);
        } else {
            s[g] = -1e30f;
        }
    }
    float mx = wave_max(mymax);
    float psum = 0.f;
#pragma unroll
    for (int g = 0; g < 4; g++) {
        int j = lane + 64 * g;
        if (j < 200) {
            float e = __expf(s[g] - mx);
            p[j] = e;
            psum += e;
        }
    }
    float tot = wave_sum(psum);
    __syncthreads();
    const int half = lane >> 5, d = lane & 31;
    const float* vb = kv + (long)(b * 200) * 384 + 192 + h * 32 + d;
    float acc = 0.f;
    for (int jj = 0; jj < 100; jj++) {
        int j = half * 100 + jj;
        acc += p[j] * vb[(long)j * 384];
    }
    acc += __shfl_xor(acc, 32, 64);
    acc /= tot;
    if (lane < 32) out[b * 192 + h * 32 + d] = acc;
}

// ---------------------------------------------------------------------------
__global__ __launch_bounds__(64) void classifier_kernel(
    const float* __restrict__ pooled,
    const float* __restrict__ g, const float* __restrict__ bt,
    const float* __restrict__ W1, const float* __restrict__ b1,
    const float* __restrict__ W2, const float* __restrict__ b2,
    const float* __restrict__ W3, const float* __restrict__ b3,
    float* __restrict__ out)
{
    __shared__ float z[192];
    __shared__ float z1[96];
    __shared__ float z2[48];
    const int b = blockIdx.x, lane = threadIdx.x;
    const float* pr = pooled + b * 192;
    float x0 = pr[lane], x1 = pr[lane + 64], x2 = pr[lane + 128];
    float m = wave_sum(x0 + x1 + x2) * (1.f / 192.f);
    float d0 = x0 - m, d1 = x1 - m, d2 = x2 - m;
    float v = wave_sum(d0 * d0 + d1 * d1 + d2 * d2) * (1.f / 192.f);
    float rs = 1.f / sqrtf(v + 1e-5f);
    z[lane]       = d0 * rs * g[lane]       + bt[lane];
    z[lane + 64]  = d1 * rs * g[lane + 64]  + bt[lane + 64];
    z[lane + 128] = d2 * rs * g[lane + 128] + bt[lane + 128];
    __syncthreads();
#pragma unroll
    for (int rep = 0; rep < 2; rep++) {
        int j = lane + rep * 64;
        if (j < 96) {
            float a = b1[j];
            for (int k = 0; k < 192; k++) a += z[k] * W1[k * 96 + j];
            z1[j] = gelu_exact(a);
        }
    }
    __syncthreads();
    if (lane < 48) {
        float a = b2[lane];
        for (int k = 0; k < 96; k++) a += z1[k] * W2[k * 48 + lane];
        z2[lane] = gelu_exact(a);
    }
    __syncthreads();
    if (lane < 2) {
        float a = b3[lane];
        for (int k = 0; k < 48; k++) a += z2[k] * W3[k * 2 + lane];
        out[b * 2 + lane] = a;
    }
}

// ---------------------------------------------------------------------------
extern "C" void kernel_launch(void* const* d_in, const int* in_sizes, int n_in,
                              void* d_out, int out_size, void* d_ws, size_t ws_size,
                              hipStream_t stream)
{
    (void)in_sizes; (void)n_in; (void)out_size; (void)ws_size;

    const float* x         = (const float*)d_in[0];
    const float* roi_W     = (const float*)d_in[1];
    const float* roi_b     = (const float*)d_in[2];
    const float* roi_ln_g  = (const float*)d_in[3];
    const float* roi_ln_b  = (const float*)d_in[4];
    const float* pos_emb   = (const float*)d_in[5];
    const float* enc_Wqkv  = (const float*)d_in[6];
    const float* enc_bqkv  = (const float*)d_in[7];
    const float* enc_Wo    = (const float*)d_in[8];
    const float* enc_bo    = (const float*)d_in[9];
    const float* enc_ln1_g = (const float*)d_in[10];
    const float* enc_ln1_b = (const float*)d_in[11];
    const float* enc_W1    = (const float*)d_in[12];
    const float* enc_b1    = (const float*)d_in[13];
    const float* enc_W2    = (const float*)d_in[14];
    const float* enc_b2    = (const float*)d_in[15];
    const float* enc_ln2_g = (const float*)d_in[16];
    const float* enc_ln2_b = (const float*)d_in[17];
    const float* pool_Wqkv = (const float*)d_in[18];
    const float* pool_bqkv = (const float*)d_in[19];
    const float* pool_Wo   = (const float*)d_in[20];
    const float* pool_bo   = (const float*)d_in[21];
    const float* cls_ln_g  = (const float*)d_in[22];
    const float* cls_ln_b  = (const float*)d_in[23];
    const float* cls_W1    = (const float*)d_in[24];
    const float* cls_b1    = (const float*)d_in[25];
    const float* cls_W2    = (const float*)d_in[26];
    const float* cls_b2    = (const float*)d_in[27];
    const float* cls_W3    = (const float*)d_in[28];
    const float* cls_b3    = (const float*)d_in[29];

    char* ws = (char*)d_ws;
    u16*   hh    = (u16*)(ws);                      // 19,660,800 B
    u16*   hl    = (u16*)(ws + 19660800);           // 19,660,800 B
    char*  bufA  = ws + 39321600;                   // 117,964,800 B
    float* bufAf = (float*)bufA;
    u16*   qkvh  = (u16*)bufA;                      // [T,576] bf16 hi
    u16*   qkvl  = (u16*)(bufA + 58982400);         // [T,576] bf16 lo
    u16*   ffh   = (u16*)bufA;                      // reuse after attn
    u16*   ffl   = (u16*)(bufA + 58982400);
    char*  bufB  = ws + 157286400;                  // 39,321,600 B
    float* bufBf = (float*)bufB;                    // fp32 [T,192]
    float* qmean = (float*)(ws + 196608000);
    float* qp    = qmean + 49152;
    float* pattn = qp + 49152;
    float* pooled= pattn + 49152;
    char*  wts   = ws + 197394432;
    u16* WqkvH = (u16*)(wts);                 // 3*576*192
    u16* WqkvL = (u16*)(wts + 663552);
    u16* Wff1H = (u16*)(wts + 1327104);       // 3*576*192
    u16* Wff1L = (u16*)(wts + 1990656);
    u16* Wff2H = (u16*)(wts + 2654208);       // 3*192*576
    u16* Wff2L = (u16*)(wts + 3317760);
    u16* WwoH  = (u16*)(wts + 3981312);       // 3*192*192
    u16* WwoL  = (u16*)(wts + 4202496);
    u16* WkvH  = (u16*)(wts + 4423680);       // 384*192
    u16* WkvL  = (u16*)(wts + 4571136);

    // ---- weight split/transpose (once per call) ----
    conv_wt<<<dim3(144, 1, 9), 256, 0, stream>>>(enc_Wqkv, WqkvH, WqkvL, 192, 192);
    conv_wt<<<dim3(432, 1, 3), 256, 0, stream>>>(enc_W1, Wff1H, Wff1L, 192, 576);
    conv_wt<<<dim3(432, 1, 3), 256, 0, stream>>>(enc_W2, Wff2H, Wff2L, 576, 192);
    conv_wt<<<dim3(144, 1, 3), 256, 0, stream>>>(enc_Wo, WwoH, WwoL, 192, 192);
    conv_wt<<<dim3(144, 1, 2), 256, 0, stream>>>(pool_Wqkv + 36864, WkvH, WkvL, 192, 192);

    // ---- tokenizer (fp32) -> bufBf [T,192] ----
    gemm_kernel<0><<<dim3(2, 3, 200), 256, 0, stream>>>(
        x, 39800, 199, roi_W, (long)199 * 192, roi_b, 192,
        bufBf, 38400, 192, 256, 192, 199, 192);
    tok_ln_pair<<<51200, 64, 0, stream>>>(bufBf, hh, hl, roi_ln_g, roi_ln_b, pos_emb);

    // ---- encoder layers ----
    for (int i = 0; i < 3; i++) {
        // qkv pairs -> qkvh/qkvl [T,576]
        gemm_mfma<3, false><<<dim3(400, 3), 256, 0, stream>>>(
            hh, hl, nullptr,
            WqkvH + (long)i * 110592, WqkvL + (long)i * 110592,
            enc_bqkv + i * 576, nullptr, qkvh, qkvl, 576, 192);
        // MFMA flash attention -> bufBf fp32 [T,192]
        attn_enc_mfma<<<1536, 256, 0, stream>>>(qkvh, qkvl, bufBf);
        // Wo (fp32 A, in-place) -> bufBf
        gemm_mfma<0, true><<<dim3(400, 1), 256, 0, stream>>>(
            nullptr, nullptr, bufBf,
            WwoH + (long)i * 36864, WwoL + (long)i * 36864,
            enc_bo + i * 192, bufBf, nullptr, nullptr, 192, 192);
        resid_ln_pair<<<51200, 64, 0, stream>>>(hh, hl, bufBf,
            enc_ln1_g + i * 192, enc_ln1_b + i * 192);
        // ff1 gelu pairs -> ffh/ffl [T,576]
        gemm_mfma<2, false><<<dim3(400, 3), 256, 0, stream>>>(
            hh, hl, nullptr,
            Wff1H + (long)i * 110592, Wff1L + (long)i * 110592,
            enc_b1 + i * 576, nullptr, ffh, ffl, 576, 192);
        // ff2 -> bufBf fp32
        gemm_mfma<0, false><<<dim3(400, 1), 256, 0, stream>>>(
            ffh, ffl, nullptr,
            Wff2H + (long)i * 110592, Wff2L + (long)i * 110592,
            enc_b2 + i * 192, bufBf, nullptr, nullptr, 192, 576);
        resid_ln_pair<<<51200, 64, 0, stream>>>(hh, hl, bufBf,
            enc_ln2_g + i * 192, enc_ln2_b + i * 192);
    }

    // ---- pooling ----
    mean_tokens_pair<<<256, 192, 0, stream>>>(hh, hl, qmean);
    gemm_kernel<0><<<dim3(2, 3, 1), 256, 0, stream>>>(
        qmean, 192, 0, pool_Wqkv, 0, pool_bqkv, 0, qp, 192, 0, 256, 192, 192, 192);
    gemm_mfma<0, false><<<dim3(400, 2), 256, 0, stream>>>(
        hh, hl, nullptr, WkvH, WkvL, pool_bqkv + 192,
        bufAf, nullptr, nullptr, 384, 192);
    attn_pool<<<1536, 64, 0, stream>>>(qp, bufAf, pattn);
    gemm_kernel<0><<<dim3(2, 3, 1), 256, 0, stream>>>(
        pattn, 192, 0, pool_Wo, 0, pool_bo, 0, pooled, 192, 0, 256, 192, 192, 192);

    // ---- classifier ----
    classifier_kernel<<<256, 64, 0, stream>>>(
        pooled, cls_ln_g, cls_ln_b,
        cls_W1, cls_b1, cls_W2, cls_b2, cls_W3, cls_b3,
        (float*)d_out);
}